// Round 3
// baseline (116.492 us; speedup 1.0000x reference)
//
#include <hip/hip_runtime.h>
#include <math.h>

#define W 128
#define STRIDE 136          // padded LDS row: [0] spare, [1..3] repl, [4..131] cols, [132..134] repl
#define LDSROWS 70

__device__ __forceinline__ float min3f(float a, float b, float c) {
    float d;
    asm("v_min3_f32 %0, %1, %2, %3" : "=v"(d) : "v"(a), "v"(b), "v"(c));
    return d;
}
__device__ __forceinline__ float max3f(float a, float b, float c) {
    float d;
    asm("v_max3_f32 %0, %1, %2, %3" : "=v"(d) : "v"(a), "v"(b), "v"(c));
    return d;
}

__global__ __launch_bounds__(256, 2) void smoaw_kernel(const float* __restrict__ x,
                                                       float* __restrict__ out) {
    const int bid   = blockIdx.x;
    const int plane = bid >> 1;
    const int half  = bid & 1;
    const int r0    = half << 6;     // 0 or 64
    const int rbase = r0 - 3;        // first staged row (clamped)

    __shared__ float lds[LDSROWS * STRIDE];   // 38080 B

    const float* __restrict__ xp = x   + (size_t)plane * (128 * W);
    float* __restrict__       op = out + (size_t)plane * (128 * W);

    const int tid = threadIdx.x;

    // Stage interior: rows rbase..rbase+69 (row-clamped) into [4..131], float4.
    for (int i = tid; i < LDSROWS * 32; i += 256) {
        const int rl = i >> 5;
        const int c4 = (i & 31) << 2;
        int rg = rbase + rl;
        rg = rg < 0 ? 0 : (rg > 127 ? 127 : rg);
        const float4 v = *reinterpret_cast<const float4*>(xp + rg * W + c4);
        *reinterpret_cast<float4*>(&lds[rl * STRIDE + 4 + c4]) = v;
    }
    // Stage replicated column pads.
    for (int j = tid; j < LDSROWS * 2; j += 256) {
        const int rl = j >> 1;
        int rg = rbase + rl;
        rg = rg < 0 ? 0 : (rg > 127 ? 127 : rg);
        if ((j & 1) == 0) {
            const float v = xp[rg * W];
            lds[rl * STRIDE + 1] = v;
            lds[rl * STRIDE + 2] = v;
            lds[rl * STRIDE + 3] = v;
        } else {
            const float v = xp[rg * W + 127];
            lds[rl * STRIDE + 132] = v;
            lds[rl * STRIDE + 133] = v;
            lds[rl * STRIDE + 134] = v;
        }
    }
    __syncthreads();

    const int c   = tid & 127;       // column owned by this thread
    const int q   = tid >> 7;        // wave-uniform (0/1)
    const int r0q = r0 + (q << 5);   // first output row
    const int r0q_u = __builtin_amdgcn_readfirstlane(r0q);

    // duplicate-count fixups to zero-padded sums (per-lane constants)
    const float cL3 = (float)((1 - c) > 0 ? (1 - c) : 0);
    const float cL5 = (float)((2 - c) > 0 ? (2 - c) : 0);
    const float cL7 = (float)((3 - c) > 0 ? (3 - c) : 0);
    const float cR3 = (float)((c - 126) > 0 ? (c - 126) : 0);
    const float cR5 = (float)((c - 125) > 0 ? (c - 125) : 0);
    const float cR7 = (float)((c - 124) > 0 ? (c - 124) : 0);

    // single tap base: pad-index c+1 .. c+7 = columns c-3 .. c+3
    const float* pb = &lds[(q << 5) * STRIDE + c + 1];
    float* ob = op + (size_t)(r0q * W + c);

    float hn3[8], hn5[8], hn7[8];
    float hx3[8], hx5[8], hx7[8];
    float p3r[8], p5r[8], p7r[8];
    float cx[4];
    float P3 = 0.f, P5 = 0.f, P7 = 0.f;
    p7r[7] = 0.f;

    float sv3_0 = 0.f, sv5_0 = 0.f, sv7_0 = 0.f;
    float sv3_b = 0.f, sv5_b = 0.f, sv7_b = 0.f;

    const float SG0 = 0.18242553f;   // sigmoid(-1.5)
    const float SG1 = 0.37754068f;   // sigmoid(-0.5)
    const float SG2 = 0.62245935f;   // sigmoid( 0.5)
    const float SG3 = 0.81757450f;   // sigmoid( 1.5)

#define STEP(S)                                                                    \
    {                                                                              \
        const float v0 = pb[(S) * STRIDE + 0];                                     \
        const float v1 = pb[(S) * STRIDE + 1];                                     \
        const float v2 = pb[(S) * STRIDE + 2];                                     \
        const float v3 = pb[(S) * STRIDE + 3];                                     \
        const float v4 = pb[(S) * STRIDE + 4];                                     \
        const float v5 = pb[(S) * STRIDE + 5];                                     \
        const float v6 = pb[(S) * STRIDE + 6];                                     \
        const float mn3 = min3f(v2, v3, v4);                                       \
        const float mn5 = min3f(mn3, v1, v5);                                      \
        const float mn7 = min3f(mn5, v0, v6);                                      \
        const float mx3 = max3f(v2, v3, v4);                                       \
        const float mx5 = max3f(mx3, v1, v5);                                      \
        const float mx7 = max3f(mx5, v0, v6);                                      \
        float s3 = v2 + v3 + v4;                                                   \
        float s5 = s3 + v1 + v5;                                                   \
        float s7 = s5 + v0 + v6;                                                   \
        s3 = s3 - cL3 * v2 - cR3 * v4;                                             \
        s5 = s5 - cL5 * v1 - cR5 * v5;                                             \
        s7 = s7 - cL7 * v0 - cR7 * v6;                                             \
        P3 += s3; P5 += s5; P7 += s7;                                              \
        hn3[(S) & 7] = mn3; hn5[(S) & 7] = mn5; hn7[(S) & 7] = mn7;                \
        hx3[(S) & 7] = mx3; hx5[(S) & 7] = mx5; hx7[(S) & 7] = mx7;                \
        p3r[(S) & 7] = P3;  p5r[(S) & 7] = P5;  p7r[(S) & 7] = P7;                 \
        cx[(S) & 3] = v3;                                                          \
        if ((S) == 0)  { sv3_0 = s3; sv5_0 = s5; sv7_0 = s7; }                     \
        if ((S) == 34) { sv3_b = s3; sv5_b = s5; sv7_b = s7; }                     \
        if ((S) >= 6) {                                                            \
            const float vm3 = min3f(hn3[((S) - 4) & 7], hn3[((S) - 3) & 7], hn3[((S) - 2) & 7]); \
            float vm5 = min3f(hn5[((S) - 5) & 7], hn5[((S) - 4) & 7], hn5[((S) - 3) & 7]);       \
            vm5 = min3f(vm5, hn5[((S) - 2) & 7], hn5[((S) - 1) & 7]);              \
            const float vm7a = min3f(hn7[((S) - 6) & 7], hn7[((S) - 5) & 7], hn7[((S) - 4) & 7]); \
            const float vm7b = min3f(hn7[((S) - 3) & 7], hn7[((S) - 2) & 7], hn7[((S) - 1) & 7]); \
            const float vm7 = min3f(vm7a, vm7b, mn7);                              \
            const float vX3 = max3f(hx3[((S) - 4) & 7], hx3[((S) - 3) & 7], hx3[((S) - 2) & 7]); \
            float vX5 = max3f(hx5[((S) - 5) & 7], hx5[((S) - 4) & 7], hx5[((S) - 3) & 7]);       \
            vX5 = max3f(vX5, hx5[((S) - 2) & 7], hx5[((S) - 1) & 7]);              \
            const float vX7a = max3f(hx7[((S) - 6) & 7], hx7[((S) - 5) & 7], hx7[((S) - 4) & 7]); \
            const float vX7b = max3f(hx7[((S) - 3) & 7], hx7[((S) - 2) & 7], hx7[((S) - 1) & 7]); \
            const float vX7 = max3f(vX7a, vX7b, mx7);                              \
            float vs3 = p3r[((S) - 2) & 7] - p3r[((S) - 5) & 7];                   \
            float vs5 = p5r[((S) - 1) & 7] - p5r[((S) - 6) & 7];                   \
            float vs7 = P7 - p7r[((S) - 7) & 7];                                   \
            if ((S) == 6 && r0q_u == 0)   { vs3 -= sv3_0; vs5 -= 2.f * sv5_0; vs7 -= 3.f * sv7_0; } \
            if ((S) == 7 && r0q_u == 0)   { vs5 -= sv5_0; vs7 -= 2.f * sv7_0; }    \
            if ((S) == 8 && r0q_u == 0)   { vs7 -= sv7_0; }                        \
            if ((S) == 35 && r0q_u == 96) { vs7 -= sv7_b; }                        \
            if ((S) == 36 && r0q_u == 96) { vs5 -= sv5_b; vs7 -= 2.f * sv7_b; }    \
            if ((S) == 37 && r0q_u == 96) { vs3 -= sv3_b; vs5 -= 2.f * sv5_b; vs7 -= 3.f * sv7_b; } \
            const float av3 = vs3 * (1.f / 9.f);                                   \
            const float av5 = vs5 * (1.f / 25.f);                                  \
            const float av7 = vs7 * (1.f / 49.f);                                  \
            const float w = (((av3 > vm3) && (av3 < vX3)) ? 1.f : 0.f)             \
                          + (((av5 > vm5) && (av5 < vX5)) ? 1.f : 0.f)             \
                          + (((av7 > vm7) && (av7 < vX7)) ? 1.f : 0.f);            \
            const float sg = (w < 0.5f) ? SG0                                      \
                           : (w < 1.5f) ? SG1                                      \
                           : (w < 2.5f) ? SG2 : SG3;                               \
            ob[((S) - 6) * W] = cx[((S) - 3) & 3] * sg;                            \
        }                                                                          \
    }

    STEP(0)  STEP(1)  STEP(2)  STEP(3)  STEP(4)  STEP(5)  STEP(6)  STEP(7)
    STEP(8)  STEP(9)  STEP(10) STEP(11) STEP(12) STEP(13) STEP(14) STEP(15)
    STEP(16) STEP(17) STEP(18) STEP(19) STEP(20) STEP(21) STEP(22) STEP(23)
    STEP(24) STEP(25) STEP(26) STEP(27) STEP(28) STEP(29) STEP(30) STEP(31)
    STEP(32) STEP(33) STEP(34) STEP(35) STEP(36) STEP(37)
#undef STEP
}

extern "C" void kernel_launch(void* const* d_in, const int* in_sizes, int n_in,
                              void* d_out, int out_size, void* d_ws, size_t ws_size,
                              hipStream_t stream) {
    const float* x = (const float*)d_in[0];
    float* out = (float*)d_out;
    const int planes = in_sizes[0] >> 14;   // 3072 planes of 128x128
    dim3 grid(planes * 2), block(256);
    hipLaunchKernelGGL(smoaw_kernel, grid, block, 0, stream, x, out);
}